// Round 13
// baseline (288.938 us; speedup 1.0000x reference)
//
#include <hip/hip_runtime.h>
#include <hip/hip_bf16.h>
#include <stdint.h>

// ---------------------------------------------------------------------------
// CrossViewIPAttnProcessor on MI355X (gfx950)
// B=8, Lq=4096, D=1024, Dc=768, H=16, HD=64, text=77 keys, ip=4 keys
// Round 13: merge phase 1 (pure read+MFMA, no staging) into phase 0 in both
// GEMMs -> 6 barriers/K-tile instead of 8. All staging/wait placement
// unchanged (b23 reads move EARLIER = strictly safer vs B-slot recycling).
// ---------------------------------------------------------------------------

typedef __attribute__((ext_vector_type(8))) short short8;
typedef __attribute__((ext_vector_type(4))) float f32x4;
typedef __attribute__((ext_vector_type(8))) float float8_t;
typedef __attribute__((ext_vector_type(8))) __bf16 bf16x8;
typedef __attribute__((ext_vector_type(4))) __bf16 bf16x4;

__device__ __forceinline__ ushort f2b(float f) {
  __bf16 h = (__bf16)f;
  return __builtin_bit_cast(ushort, h);
}

__device__ __forceinline__ short8 pack2(float4 a, float4 b) {
  float8_t v;
  v[0] = a.x; v[1] = a.y; v[2] = a.z; v[3] = a.w;
  v[4] = b.x; v[5] = b.y; v[6] = b.z; v[7] = b.w;
  return __builtin_bit_cast(short8, __builtin_convertvector(v, bf16x8));
}

#define GLD16(gp, lp) \
  __builtin_amdgcn_global_load_lds((const __attribute__((address_space(1))) uint32_t*)(gp), \
                                   (__attribute__((address_space(3))) uint32_t*)(lp), 16, 0, 0)

#define FENCE_SCHED() __builtin_amdgcn_sched_barrier(0)

// -------- 1+2) fused prep: 6 weight fp32->bf16 segs + Xn builder -----------
struct CvtArgs {
  const float* src[6];
  ushort* dst[6];
  int n4[6];
};

__global__ __launch_bounds__(256) void k_prep(CvtArgs a,
                                              const float* __restrict__ enc,
                                              const float* __restrict__ lnw,
                                              const float* __restrict__ lnb,
                                              ushort* __restrict__ xn) {
  int seg = blockIdx.y;
  if (seg < 6) {
    int i = blockIdx.x * blockDim.x + threadIdx.x;
    if (i >= a.n4[seg]) return;
    float4 v = reinterpret_cast<const float4*>(a.src[seg])[i];
    bf16x4 h;
    h[0] = (__bf16)v.x; h[1] = (__bf16)v.y; h[2] = (__bf16)v.z; h[3] = (__bf16)v.w;
    reinterpret_cast<ushort4*>(a.dst[seg])[i] = __builtin_bit_cast(ushort4, h);
    return;
  }
  // seg == 6: Xn builder (768 blocks used)
  if (blockIdx.x >= 768) return;
  const int Dc = 768;
  int tok = blockIdx.x % 96, b = blockIdx.x / 96, t = threadIdx.x;
  ushort* out = xn + ((size_t)b * 96 + tok) * Dc;
  bool padrow = (tok >= 84) || (tok >= 77 && tok < 80);
  if (padrow) { out[t] = 0; out[t + 256] = 0; out[t + 512] = 0; return; }
  const float* src = (tok < 77) ? enc + ((size_t)b * 81 + tok) * Dc
                                : enc + ((size_t)b * 81 + 77 + (tok - 80)) * Dc;
  float x0 = src[t], x1 = src[t + 256], x2 = src[t + 512];
  if (tok >= 80) { out[t] = f2b(x0); out[t + 256] = f2b(x1); out[t + 512] = f2b(x2); return; }
  float s = x0 + x1 + x2, q = x0 * x0 + x1 * x1 + x2 * x2;
  for (int m = 32; m; m >>= 1) { s += __shfl_xor(s, m, 64); q += __shfl_xor(q, m, 64); }
  __shared__ float rs[4], rq[4];
  int w = t >> 6;
  if ((t & 63) == 0) { rs[w] = s; rq[w] = q; }
  __syncthreads();
  s = rs[0] + rs[1] + rs[2] + rs[3];
  q = rq[0] + rq[1] + rq[2] + rq[3];
  float mean = s * (1.0f / 768.0f);
  float var = q * (1.0f / 768.0f) - mean * mean;
  float rstd = rsqrtf(var + 1e-5f);
  out[t]       = f2b((x0 - mean) * rstd * lnw[t]       + lnb[t]);
  out[t + 256] = f2b((x1 - mean) * rstd * lnw[t + 256] + lnb[t + 256]);
  out[t + 512] = f2b((x2 - mean) * rstd * lnw[t + 512] + lnb[t + 512]);
}

// ------------- 3) K/V projection (grid 16x8x2, 64-col tiles) ---------------
__global__ __launch_bounds__(256) void k_kv(const ushort* __restrict__ xn,
                                            const ushort* __restrict__ wk,
                                            const ushort* __restrict__ wkip,
                                            const ushort* __restrict__ wv,
                                            const ushort* __restrict__ wvip,
                                            ushort* __restrict__ kall,
                                            ushort* __restrict__ vtall) {
  int mode = blockIdx.z;
  const ushort* wb   = mode ? wv   : wk;
  const ushort* wipb = mode ? wvip : wkip;
  ushort* out        = mode ? vtall : kall;
  int n0 = blockIdx.x * 64, b = blockIdx.y;
  int t = threadIdx.x, w = t >> 6, l = t & 63, lo = l & 15, hi = l >> 4;
  __shared__ alignas(16) ushort Xs[96 * 32];
  __shared__ alignas(16) ushort Ws[64 * 32];
  __shared__ alignas(16) ushort Wip[64 * 32];
  f32x4 acc[6];
  f32x4 zf = {0.f, 0.f, 0.f, 0.f};
  for (int i = 0; i < 6; i++) acc[i] = zf;
  const ushort* xb = xn + (size_t)b * 96 * 768;
  for (int k0 = 0; k0 < 768; k0 += 32) {
    __syncthreads();
    for (int i = t; i < 96 * 16; i += 256) {
      int row = i >> 4, p = i & 15;
      reinterpret_cast<uint32_t*>(Xs)[i] =
          *reinterpret_cast<const uint32_t*>(xb + row * 768 + k0 + p * 2);
    }
    for (int i = t; i < 64 * 16; i += 256) {
      int row = i >> 4, p = i & 15;
      reinterpret_cast<uint32_t*>(Ws)[i] =
          *reinterpret_cast<const uint32_t*>(wb + (size_t)(n0 + row) * 768 + k0 + p * 2);
      reinterpret_cast<uint32_t*>(Wip)[i] =
          *reinterpret_cast<const uint32_t*>(wipb + (size_t)(n0 + row) * 768 + k0 + p * 2);
    }
    __syncthreads();
    short8 a[6], bb, bip;
    for (int mi = 0; mi < 6; mi++)
      a[mi] = *reinterpret_cast<const short8*>(Xs + (mi * 16 + lo) * 32 + hi * 8);
    bb  = *reinterpret_cast<const short8*>(Ws  + (w * 16 + lo) * 32 + hi * 8);
    bip = *reinterpret_cast<const short8*>(Wip + (w * 16 + lo) * 32 + hi * 8);
    for (int mi = 0; mi < 5; mi++)
      acc[mi] = __builtin_amdgcn_mfma_f32_16x16x32_bf16(a[mi], bb, acc[mi], 0, 0, 0);
    acc[5] = __builtin_amdgcn_mfma_f32_16x16x32_bf16(a[5], bip, acc[5], 0, 0, 0);
  }
  for (int mi = 0; mi < 6; mi++) {
    int col = n0 + w * 16 + lo;
    int h = col >> 6, dd = col & 63;
    for (int j = 0; j < 4; j++) {
      int tok = mi * 16 + hi * 4 + j;
      ushort v = f2b(acc[mi][j]);
      if (mode == 0) out[(((size_t)b * 16 + h) * 96 + tok) * 64 + dd] = v;
      else           out[(((size_t)b * 16 + h) * 64 + dd) * 96 + tok] = v;
    }
  }
}

// ---------- 4+5) Q GEMM (3-phase/K-tile, fp32 A reg-staged) + attention ----
__global__ __launch_bounds__(512, 2) void k_qg8(const float* __restrict__ A,
                                                const ushort* __restrict__ Bw,
                                                const ushort* __restrict__ Kall,
                                                const ushort* __restrict__ Vt,
                                                ushort* __restrict__ attnO) {
  const int K = 1024, NT = 16;
  int wg = blockIdx.x;
  int nid = (wg & 7) * 64 + (wg >> 3);      // XCD-chunked, nwg=512 (%8==0)
  int m0 = (nid >> 2) * 256, n0 = (nid & 3) * 256;
  int t = threadIdx.x, wid = t >> 6, l = t & 63, lo = l & 15, hi = l >> 4;
  int wr = wid >> 2, wc = wid & 3;
  __shared__ alignas(16) ushort SMEM[81920];        // 160KB
  ushort* ASb = SMEM;                                // A dbuf: 2 x 32KB
  ushort* BSb = SMEM + 32768;                        // B dbuf: 2 x 32KB
  f32x4 acc[8][4];
  f32x4 zf = {0.f, 0.f, 0.f, 0.f};
#pragma unroll
  for (int i = 0; i < 8; i++)
#pragma unroll
    for (int j = 0; j < 4; j++) acc[i][j] = zf;
  int tr = t >> 3, tc = t & 7;
  int tcs = tc ^ (tr & 7);                  // T2 pre-swizzled source chunk
  const float*  gA = A  + (size_t)(m0 + tr) * K + tcs * 8;
  const ushort* gB = Bw + (size_t)(n0 + tr) * K + tcs * 8;
  float4 av[4][2];

#define LD_A(kt_) do { \
    _Pragma("unroll") \
    for (int s_ = 0; s_ < 4; s_++) { \
      av[s_][0] = *reinterpret_cast<const float4*>(gA + (size_t)s_ * 64 * K + (kt_) * 64); \
      av[s_][1] = *reinterpret_cast<const float4*>(gA + (size_t)s_ * 64 * K + (kt_) * 64 + 4); \
    } } while (0)
#define WR_A(s_, b_) \
    *reinterpret_cast<short8*>(&ASb[(b_) * 16384 + (s_) * 4096 + t * 8]) = pack2(av[s_][0], av[s_][1])
#define STG_B(kt_, s_, b_) GLD16(gB + (size_t)(s_) * 64 * K + (kt_) * 64, &BSb[(b_) * 16384 + (s_) * 4096 + wid * 512])

  // ---- prologue ----
  LD_A(0);
  STG_B(0, 0, 0); STG_B(0, 1, 0); STG_B(0, 2, 0); STG_B(0, 3, 0);
  STG_B(1, 0, 1); STG_B(1, 1, 1); STG_B(1, 2, 1); STG_B(1, 3, 1);
  WR_A(0, 0); WR_A(1, 0); WR_A(2, 0); WR_A(3, 0);
  LD_A(1);
  WR_A(0, 1); WR_A(1, 1); WR_A(2, 1); WR_A(3, 1);
  asm volatile("s_waitcnt lgkmcnt(0)" ::: "memory");
  __builtin_amdgcn_s_barrier();
  FENCE_SCHED();

  const int swz = (lo & 7) << 3;
  short8 af[4][2], af2[4][2], b01[2][2], b23[2][2];

  for (int kt = 0; kt < NT; kt++) {
    int cur = kt & 1, nxt = cur ^ 1;
    const ushort* sA = &ASb[cur * 16384];
    const ushort* sB = &BSb[cur * 16384];
    // phase 0 (merged): af + b01 + b23 reads; MFMA q03 x n0123 (32)
#pragma unroll
    for (int q = 0; q < 4; q++)
#pragma unroll
      for (int kk = 0; kk < 2; kk++)
        af[q][kk] = *reinterpret_cast<const short8*>(
            sA + (wr * 128 + q * 16 + lo) * 64 + ((hi * 8 + kk * 32) ^ swz));
#pragma unroll
    for (int n = 0; n < 2; n++)
#pragma unroll
      for (int kk = 0; kk < 2; kk++) {
        b01[n][kk] = *reinterpret_cast<const short8*>(
            sB + (wc * 64 + n * 16 + lo) * 64 + ((hi * 8 + kk * 32) ^ swz));
        b23[n][kk] = *reinterpret_cast<const short8*>(
            sB + (wc * 64 + (2 + n) * 16 + lo) * 64 + ((hi * 8 + kk * 32) ^ swz));
      }
    __builtin_amdgcn_s_barrier();
    FENCE_SCHED();
    __builtin_amdgcn_s_setprio(1);
#pragma unroll
    for (int q = 0; q < 4; q++)
#pragma unroll
      for (int n = 0; n < 2; n++)
#pragma unroll
        for (int kk = 0; kk < 2; kk++) {
          acc[q][n]     = __builtin_amdgcn_mfma_f32_16x16x32_bf16(af[q][kk], b01[n][kk], acc[q][n], 0, 0, 0);
          acc[q][2 + n] = __builtin_amdgcn_mfma_f32_16x16x32_bf16(af[q][kk], b23[n][kk], acc[q][2 + n], 0, 0, 0);
        }
    __builtin_amdgcn_s_setprio(0);
    __builtin_amdgcn_s_barrier();
    FENCE_SCHED();
    // phase 2: af2 reads; B(t+2)s01; A(t+1)s01 writes (implicit vmcnt wait
    //          on av, issued p3 of t-1 = 2+ phases of cover); MFMA q47xn23
#pragma unroll
    for (int q = 0; q < 4; q++)
#pragma unroll
      for (int kk = 0; kk < 2; kk++)
        af2[q][kk] = *reinterpret_cast<const short8*>(
            sA + (wr * 128 + (4 + q) * 16 + lo) * 64 + ((hi * 8 + kk * 32) ^ swz));
    if (kt + 2 < NT) { STG_B(kt + 2, 0, cur); STG_B(kt + 2, 1, cur); }
    if (kt + 1 < NT) { WR_A(0, nxt); WR_A(1, nxt); }
    __builtin_amdgcn_s_barrier();
    FENCE_SCHED();
    __builtin_amdgcn_s_setprio(1);
#pragma unroll
    for (int q = 0; q < 4; q++)
#pragma unroll
      for (int n = 0; n < 2; n++)
#pragma unroll
        for (int kk = 0; kk < 2; kk++)
          acc[4 + q][2 + n] = __builtin_amdgcn_mfma_f32_16x16x32_bf16(af2[q][kk], b23[n][kk], acc[4 + q][2 + n], 0, 0, 0);
    __builtin_amdgcn_s_setprio(0);
    __builtin_amdgcn_s_barrier();
    FENCE_SCHED();
    // phase 3: B(t+2)s23; A(t+1)s23 writes; vmcnt(4); lgkmcnt(0);
    //          LD_A(t+2) issued AFTER the drains; MFMA q47xn01
    if (kt + 2 < NT) { STG_B(kt + 2, 2, cur); STG_B(kt + 2, 3, cur); }
    if (kt + 1 < NT) { WR_A(2, nxt); WR_A(3, nxt); }
    asm volatile("s_waitcnt vmcnt(4)" ::: "memory");
    asm volatile("s_waitcnt lgkmcnt(0)" ::: "memory");
    if (kt + 2 < NT) LD_A(kt + 2);
    __builtin_amdgcn_s_barrier();
    FENCE_SCHED();
    __builtin_amdgcn_s_setprio(1);
#pragma unroll
    for (int q = 0; q < 4; q++)
#pragma unroll
      for (int n = 0; n < 2; n++)
#pragma unroll
        for (int kk = 0; kk < 2; kk++)
          acc[4 + q][n] = __builtin_amdgcn_mfma_f32_16x16x32_bf16(af2[q][kk], b01[n][kk], acc[4 + q][n], 0, 0, 0);
    __builtin_amdgcn_s_setprio(0);
    __builtin_amdgcn_s_barrier();
    FENCE_SCHED();
  }
#undef LD_A
#undef WR_A
#undef STG_B

  // =================== fused attention epilogue (per wave) ==================
  __syncthreads();                       // all waves done with AS/BS
  // (a) stage Q tile: wave-local [128][64], chunk ^ (row&7) swizzle
  ushort* ep = SMEM + wid * 8192;
#pragma unroll
  for (int mi = 0; mi < 8; mi++)
#pragma unroll
    for (int n = 0; n < 4; n++)
#pragma unroll
      for (int j = 0; j < 4; j++) {
        int row_l = mi * 16 + hi * 4 + j;
        int col = n * 16 + lo;
        ep[row_l * 64 + (((col >> 3) ^ (row_l & 7)) << 3) + (col & 7)] = f2b(acc[mi][n][j]);
      }
  // (b) per-wave head attention; no-max softmax (bounded scores), P holds
  //     unnormalized exp (ip pre-scaled by sb/si); o scaled by rb post-PV.
  ushort* PS = SMEM + 65536 + wid * 2048;     // 4KB P / out scratch
  int b = m0 >> 12;
  int h = (n0 >> 6) + wc;
  const ushort* Kb = Kall + (size_t)(b * 16 + h) * 96 * 64;
  const ushort* Vb = Vt + (size_t)(b * 16 + h) * 64 * 96;
  short8 kf[6][2], vf[3][4];
#pragma unroll
  for (int ni = 0; ni < 6; ni++)
#pragma unroll
    for (int ks = 0; ks < 2; ks++)
      kf[ni][ks] = *reinterpret_cast<const short8*>(Kb + (ni * 16 + lo) * 64 + ks * 32 + hi * 8);
#pragma unroll
  for (int kk = 0; kk < 3; kk++)
#pragma unroll
    for (int dn = 0; dn < 4; dn++)
      vf[kk][dn] = *reinterpret_cast<const short8*>(Vb + (dn * 16 + lo) * 96 + kk * 32 + hi * 8);
  const float SC = 0.125f * 1.44269504088896340736f;  // 1/sqrt(64) * log2(e)

  short8 qf[2];
  f32x4 s[6];
#define QK_LOAD(mi_) do { \
    _Pragma("unroll") \
    for (int ks = 0; ks < 2; ks++) \
      qf[ks] = *reinterpret_cast<const short8*>( \
          &ep[((mi_) * 16 + lo) * 64 + (((ks * 4 + hi) ^ (lo & 7)) << 3)]); \
  } while (0)
#define QK_MFMA() do { \
    _Pragma("unroll") \
    for (int ni = 0; ni < 6; ni++) { \
      s[ni] = zf; \
      _Pragma("unroll") \
      for (int ks = 0; ks < 2; ks++) \
        s[ni] = __builtin_amdgcn_mfma_f32_16x16x32_bf16(qf[ks], kf[ni][ks], s[ni], 0, 0, 0); \
    } } while (0)

  QK_LOAD(0); QK_MFMA();
  for (int mi = 0; mi < 8; mi++) {
    float rb4[4];
#pragma unroll
    for (int j = 0; j < 4; j++) {
      float pb[5];
      float sb = 0.f;
#pragma unroll
      for (int ni = 0; ni < 5; ni++) {
        int c = ni * 16 + lo;
        float p = (c < 77) ? exp2f(s[ni][j] * SC) : 0.f;
        pb[ni] = p; sb += p;
      }
      sb += __shfl_xor(sb, 1, 64); sb += __shfl_xor(sb, 2, 64);
      sb += __shfl_xor(sb, 4, 64); sb += __shfl_xor(sb, 8, 64);
      rb4[j] = __builtin_amdgcn_rcpf(sb);
      // ip softmax over lanes lo<4 (cols 80..83); masked-lane write guarded
      bool val = lo < 4;
      float pi = val ? exp2f(s[5][j] * SC) : 0.f;
      float si = pi;
      si += __shfl_xor(si, 1, 64); si += __shfl_xor(si, 2, 64);
      ushort* pr = &PS[(hi * 4 + j) * 104];
#pragma unroll
      for (int ni = 0; ni < 5; ni++) pr[ni * 16 + lo] = f2b(pb[ni]);
      pr[80 + lo] = f2b(val ? pi * (sb * __builtin_amdgcn_rcpf(si)) : 0.f);
    }
    // QK for next mi sits between P-write and PV-read (covers DS latency)
    if (mi < 7) { QK_LOAD(mi + 1); QK_MFMA(); }
    // PV (unnormalized P)
    f32x4 o[4];
#pragma unroll
    for (int dn = 0; dn < 4; dn++) o[dn] = zf;
#pragma unroll
    for (int kk = 0; kk < 3; kk++) {
      short8 pf = *reinterpret_cast<const short8*>(&PS[lo * 104 + kk * 32 + hi * 8]);
#pragma unroll
      for (int dn = 0; dn < 4; dn++)
        o[dn] = __builtin_amdgcn_mfma_f32_16x16x32_bf16(pf, vf[kk][dn], o[dn], 0, 0, 0);
    }
    // scale by rb; stage via chunk^row swizzle; coalesced 16B stores
#pragma unroll
    for (int dn = 0; dn < 4; dn++)
#pragma unroll
      for (int j = 0; j < 4; j++) {
        int row_l = hi * 4 + j;
        int col = dn * 16 + lo;
        PS[row_l * 64 + (((col >> 3) ^ (row_l & 7)) << 3) + (col & 7)] = f2b(o[dn][j] * rb4[j]);
      }
    int gr0 = m0 + wr * 128 + mi * 16;
#pragma unroll
    for (int it = 0; it < 2; it++) {
      int row_o = it * 8 + (l >> 3), c8 = l & 7;
      short8 v = *reinterpret_cast<const short8*>(
          &PS[row_o * 64 + ((c8 ^ (row_o & 7)) << 3)]);
      *reinterpret_cast<short8*>(&attnO[(size_t)(gr0 + row_o) * 1024 + h * 64 + c8 * 8]) = v;
    }
  }
#undef QK_LOAD
#undef QK_MFMA
}

// ------------- 6) out GEMM: 3-phase/K-tile, bf16 A, fp32 C + bias ----------
__global__ __launch_bounds__(512, 2) void k_og8(const ushort* __restrict__ A,
                                                const ushort* __restrict__ Bw,
                                                const float* __restrict__ bias,
                                                float* __restrict__ C) {
  const int K = 1024, NT = 16;
  int wg = blockIdx.x;
  int nid = (wg & 7) * 64 + (wg >> 3);
  int m0 = (nid >> 2) * 256, n0 = (nid & 3) * 256;
  int t = threadIdx.x, wid = t >> 6, l = t & 63, lo = l & 15, hi = l >> 4;
  int wr = wid >> 2, wc = wid & 3;
  __shared__ alignas(16) ushort AS[2][256 * 64];
  __shared__ alignas(16) ushort BS[2][256 * 64];
  f32x4 acc[8][4];
  f32x4 zf = {0.f, 0.f, 0.f, 0.f};
#pragma unroll
  for (int i = 0; i < 8; i++)
#pragma unroll
    for (int j = 0; j < 4; j++) acc[i][j] = zf;
  int tr = t >> 3, tc = t & 7;
  int tcs = tc ^ (tr & 7);
  const ushort* gA = A  + (size_t)(m0 + tr) * K + tcs * 8;
  const ushort* gB = Bw + (size_t)(n0 + tr) * K + tcs * 8;

#define STG_A(kt_, s_, b_) GLD16(gA + (size_t)(s_) * 64 * K + (kt_) * 64, &AS[b_][(s_) * 4096 + wid * 512])
#define STG_B(kt_, s_, b_) GLD16(gB + (size_t)(s_) * 64 * K + (kt_) * 64, &BS[b_][(s_) * 4096 + wid * 512])

  STG_A(0, 0, 0); STG_A(0, 1, 0); STG_A(0, 2, 0); STG_A(0, 3, 0);
  STG_B(0, 0, 0); STG_B(0, 1, 0); STG_B(0, 2, 0); STG_B(0, 3, 0);
  STG_B(1, 0, 1); STG_B(1, 1, 1); STG_B(1, 2, 1); STG_B(1, 3, 1);
  STG_A(1, 0, 1); STG_A(1, 1, 1);
  asm volatile("s_waitcnt vmcnt(6)" ::: "memory");
  __builtin_amdgcn_s_barrier();
  FENCE_SCHED();

  const int swz = (lo & 7) << 3;
  short8 af[4][2], af2[4][2], b01[2][2], b23[2][2];

  for (int kt = 0; kt < NT; kt++) {
    int cur = kt & 1, nxt = cur ^ 1;
    const ushort* sA = &AS[cur][0];
    const ushort* sB = &BS[cur][0];
    // phase 0 (merged): af + b01 + b23 reads; A(t+1)s23 stage; 32 MFMA
#pragma unroll
    for (int q = 0; q < 4; q++)
#pragma unroll
      for (int kk = 0; kk < 2; kk++)
        af[q][kk] = *reinterpret_cast<const short8*>(
            sA + (wr * 128 + q * 16 + lo) * 64 + ((hi * 8 + kk * 32) ^ swz));
#pragma unroll
    for (int n = 0; n < 2; n++)
#pragma unroll
      for (int kk = 0; kk < 2; kk++) {
        b01[n][kk] = *reinterpret_cast<const short8*>(
            sB + (wc * 64 + n * 16 + lo) * 64 + ((hi * 8 + kk * 32) ^ swz));
        b23[n][kk] = *reinterpret_cast<const short8*>(
            sB + (wc * 64 + (2 + n) * 16 + lo) * 64 + ((hi * 8 + kk * 32) ^ swz));
      }
    if (kt + 1 < NT) { STG_A(kt + 1, 2, nxt); STG_A(kt + 1, 3, nxt); }
    __builtin_amdgcn_s_barrier();
    FENCE_SCHED();
    __builtin_amdgcn_s_setprio(1);
#pragma unroll
    for (int q = 0; q < 4; q++)
#pragma unroll
      for (int n = 0; n < 2; n++)
#pragma unroll
        for (int kk = 0; kk < 2; kk++) {
          acc[q][n]     = __builtin_amdgcn_mfma_f32_16x16x32_bf16(af[q][kk], b01[n][kk], acc[q][n], 0, 0, 0);
          acc[q][2 + n] = __builtin_amdgcn_mfma_f32_16x16x32_bf16(af[q][kk], b23[n][kk], acc[q][2 + n], 0, 0, 0);
        }
    __builtin_amdgcn_s_setprio(0);
    __builtin_amdgcn_s_barrier();
    FENCE_SCHED();
    // phase 2
#pragma unroll
    for (int q = 0; q < 4; q++)
#pragma unroll
      for (int kk = 0; kk < 2; kk++)
        af2[q][kk] = *reinterpret_cast<const short8*>(
            sA + (wr * 128 + (4 + q) * 16 + lo) * 64 + ((hi * 8 + kk * 32) ^ swz));
    if (kt + 2 < NT) { STG_B(kt + 2, 0, cur); STG_B(kt + 2, 1, cur); }
    __builtin_amdgcn_s_barrier();
    FENCE_SCHED();
    __builtin_amdgcn_s_setprio(1);
#pragma unroll
    for (int q = 0; q < 4; q++)
#pragma unroll
      for (int n = 0; n < 2; n++)
#pragma unroll
        for (int kk = 0; kk < 2; kk++)
          acc[4 + q][2 + n] = __builtin_amdgcn_mfma_f32_16x16x32_bf16(af2[q][kk], b23[n][kk], acc[4 + q][2 + n], 0, 0, 0);
    __builtin_amdgcn_s_setprio(0);
    __builtin_amdgcn_s_barrier();
    FENCE_SCHED();
    // phase 3
    if (kt + 2 < NT) {
      STG_B(kt + 2, 2, cur); STG_B(kt + 2, 3, cur);
      STG_A(kt + 2, 0, cur); STG_A(kt + 2, 1, cur);
      asm volatile("s_waitcnt vmcnt(6)" ::: "memory");
    } else {
      asm volatile("s_waitcnt vmcnt(0)" ::: "memory");
    }
    __builtin_amdgcn_s_barrier();
    FENCE_SCHED();
    __builtin_amdgcn_s_setprio(1);
#pragma unroll
    for (int q = 0; q < 4; q++)
#pragma unroll
      for (int n = 0; n < 2; n++)
#pragma unroll
        for (int kk = 0; kk < 2; kk++)
          acc[4 + q][n] = __builtin_amdgcn_mfma_f32_16x16x32_bf16(af2[q][kk], b01[n][kk], acc[4 + q][n], 0, 0, 0);
    __builtin_amdgcn_s_setprio(0);
    __builtin_amdgcn_s_barrier();
    FENCE_SCHED();
  }
#pragma unroll
  for (int n = 0; n < 4; n++) {
    int c = n0 + wc * 64 + n * 16 + lo;
    float bv = bias[c];
#pragma unroll
    for (int mi = 0; mi < 8; mi++)
#pragma unroll
      for (int j = 0; j < 4; j++) {
        int r = m0 + wr * 128 + mi * 16 + hi * 4 + j;
        C[(size_t)r * 1024 + c] = acc[mi][n][j] + bv;
      }
  }
#undef STG_A
#undef STG_B
}

// ---------------------------------------------------------------------------
extern "C" void kernel_launch(void* const* d_in, const int* in_sizes, int n_in,
                              void* d_out, int out_size, void* d_ws, size_t ws_size,
                              hipStream_t stream) {
  const float* hs   = (const float*)d_in[0];
  const float* enc  = (const float*)d_in[1];
  const float* Wq   = (const float*)d_in[2];
  const float* Wk   = (const float*)d_in[3];
  const float* Wv   = (const float*)d_in[4];
  const float* Wkip = (const float*)d_in[5];
  const float* Wvip = (const float*)d_in[6];
  const float* Wo   = (const float*)d_in[7];
  const float* bo   = (const float*)d_in[8];
  const float* lnw  = (const float*)d_in[9];
  const float* lnb  = (const float*)d_in[10];
  float* out = (float*)d_out;

  ushort* p = (ushort*)d_ws;
  ushort* attn    = p; p += (size_t)32768 * 1024;
  ushort* wq_bf   = p; p += (size_t)1024 * 1024;
  ushort* wo_bf   = p; p += (size_t)1024 * 1024;
  ushort* wk_bf   = p; p += (size_t)1024 * 768;
  ushort* wkip_bf = p; p += (size_t)1024 * 768;
  ushort* wv_bf   = p; p += (size_t)1024 * 768;
  ushort* wvip_bf = p; p += (size_t)1024 * 768;
  ushort* xn      = p; p += (size_t)8 * 96 * 768;
  ushort* kall    = p; p += (size_t)8 * 16 * 96 * 64;
  ushort* vtall   = p; p += (size_t)8 * 16 * 96 * 64;

  CvtArgs ca;
  ca.src[0] = Wq;   ca.dst[0] = wq_bf;   ca.n4[0] = 262144;
  ca.src[1] = Wo;   ca.dst[1] = wo_bf;   ca.n4[1] = 262144;
  ca.src[2] = Wk;   ca.dst[2] = wk_bf;   ca.n4[2] = 196608;
  ca.src[3] = Wkip; ca.dst[3] = wkip_bf; ca.n4[3] = 196608;
  ca.src[4] = Wv;   ca.dst[4] = wv_bf;   ca.n4[4] = 196608;
  ca.src[5] = Wvip; ca.dst[5] = wvip_bf; ca.n4[5] = 196608;
  k_prep<<<dim3(1024, 7), 256, 0, stream>>>(ca, enc, lnw, lnb, xn);
  k_kv<<<dim3(16, 8, 2), 256, 0, stream>>>(xn, wk_bf, wkip_bf, wv_bf, wvip_bf, kall, vtall);
  k_qg8<<<512, 512, 0, stream>>>(hs, wq_bf, kall, vtall, attn);
  k_og8<<<512, 512, 0, stream>>>(attn, wo_bf, bo, out);
}